// Round 1
// baseline (824.528 us; speedup 1.0000x reference)
//
#include <hip/hip_runtime.h>
#include <cstdint>
#include <cstddef>

// ---------------------------------------------------------------------------
// AlphaNet: features -> BN -> conv(1x3,16) -> relu -> fc1(43200->512) -> relu
//          -> fc2(512->128) -> sigmoid -> fc3(128->1)
// fc1 is the 181-GFLOP GEMM -> f16 MFMA (A pre-scaled by 2^-8 for range).
// ---------------------------------------------------------------------------

typedef _Float16 f16;
typedef f16 f16x8 __attribute__((ext_vector_type(8)));
typedef f16 f16x4 __attribute__((ext_vector_type(4)));
typedef float f32x4 __attribute__((ext_vector_type(4)));

#define N_TOTAL 4096
#define CHUNK   2048          // samples per pipeline pass (2 passes)
#define K_FC1   43200         // 16*270*10
#define SPLITK  10
#define KC      (K_FC1 / SPLITK)   // 4320
#define GITERS  (KC / 32)          // 135
#define MT_CHUNK (CHUNK / 128)     // 16 M-tiles per chunk

__device__ __forceinline__ float fillv(float x) { return isfinite(x) ? x : 0.0f; }

// ---------------------------------------------------------------------------
// Kernel 1: fc1_w fp32 -> f16  (22.1M elements)
// ---------------------------------------------------------------------------
__global__ __launch_bounds__(256) void conv_w_f16(const float* __restrict__ w,
                                                  f16* __restrict__ w16) {
    int t = blockIdx.x * 256 + threadIdx.x;          // grid covers exactly 22118400/4
    float4 v = ((const float4*)w)[t];
    f16x4 o = { (f16)v.x, (f16)v.y, (f16)v.z, (f16)v.w };
    ((f16x4*)w16)[t] = o;
}

// ---------------------------------------------------------------------------
// Kernel 2: per-sample features + BN + conv + relu -> A16 (scaled 2^-8)
// One block per sample, 256 threads.
// Feature rows: corr 0-104 | cov 105-209 | std 210-224 | zs 225-239
//               | ret 240-254 | dl 255-269 ; 12 windows each.
// ---------------------------------------------------------------------------
__global__ __launch_bounds__(256) void stage_a(
    const float* __restrict__ data, const float* __restrict__ bn_g,
    const float* __restrict__ bn_b, const float* __restrict__ bn_m,
    const float* __restrict__ bn_v, const float* __restrict__ conv_w,
    const float* __restrict__ conv_b, f16* __restrict__ A16, int n0)
{
    __shared__ float raw[1800];        // raw window data, becomes spread
    __shared__ float feat[270 * 12];
    __shared__ float cw[48];
    __shared__ float cb[16];
    __shared__ int   pi[105], pj[105];

    const int t = threadIdx.x;
    const int n = n0 + blockIdx.x;
    const float* src = data + (size_t)n * 1800;
    for (int i = t; i < 1800; i += 256) raw[i] = src[i];
    if (t < 48)  cw[t] = conv_w[t];
    if (t < 16)  cb[t] = conv_b[t];
    if (t < 105) {                               // triu_indices(15, k=1) order
        int i = 0, rem = t;
        while (rem >= 14 - i) { rem -= 14 - i; ++i; }
        pi[t] = i; pj[t] = i + 1 + rem;
    }
    __syncthreads();

    // per-(f,w) stats; overwrite raw with spread
    if (t < 180) {
        int f = t / 12, w = t % 12;
        int base = f * 120 + w * 10;
        float x[10];
        #pragma unroll
        for (int s = 0; s < 10; ++s) x[s] = raw[base + s];
        float sum = 0.f;
        #pragma unroll
        for (int s = 0; s < 10; ++s) sum += x[s];
        float mean = sum * 0.1f;
        float ret = x[9] / x[0] - 1.0f;
        float dl = 0.f;
        #pragma unroll
        for (int s = 0; s < 10; ++s) dl += x[s] * ((float)(s + 1) * (1.0f / 55.0f));
        float var = 0.f;
        #pragma unroll
        for (int s = 0; s < 10; ++s) { float d = x[s] - mean; raw[base + s] = d; var += d * d; }
        var *= (1.0f / 9.0f);                    // unbiased
        float sd = sqrtf(var);
        feat[(210 + f) * 12 + w] = fillv(sd);
        feat[(225 + f) * 12 + w] = fillv(mean / sd);
        feat[(240 + f) * 12 + w] = fillv(ret);
        feat[(255 + f) * 12 + w] = fillv(dl);
    }
    __syncthreads();

    // pairwise cov / corr
    for (int q = t; q < 1260; q += 256) {
        int p = q / 12, w = q % 12;
        int i = pi[p], j = pj[p];
        int bi = i * 120 + w * 10, bj = j * 120 + w * 10;
        float cv = 0.f;
        #pragma unroll
        for (int s = 0; s < 10; ++s) cv += raw[bi + s] * raw[bj + s];
        cv *= (1.0f / 9.0f);
        float si = feat[(210 + i) * 12 + w], sj = feat[(210 + j) * 12 + w];
        feat[p * 12 + w]         = fillv(cv / (si * sj) * 0.9f);  // *(S-1)/S
        feat[(105 + p) * 12 + w] = fillv(cv);
    }
    __syncthreads();

    // BatchNorm (eval, C=1 scalar)
    float a  = bn_g[0] * rsqrtf(bn_v[0] + 1e-5f);
    float bb = bn_b[0] - bn_m[0] * a;
    for (int i = t; i < 3240; i += 256) feat[i] = feat[i] * a + bb;
    __syncthreads();

    // conv(1x3) + bias + relu -> scale 2^-8 -> clamp -> f16
    f16* dst = A16 + (size_t)blockIdx.x * K_FC1;
    for (int idx = t; idx < K_FC1; idx += 256) {
        int o = idx / 2700;
        int rem = idx - o * 2700;
        int h = rem / 10;
        int wo = rem - h * 10;
        const float* fr = feat + h * 12 + wo;
        float y = cb[o] + cw[o * 3] * fr[0] + cw[o * 3 + 1] * fr[1] + cw[o * 3 + 2] * fr[2];
        y = y > 0.f ? y : 0.f;
        y *= 0.00390625f;                        // 2^-8 (exact)
        y = y < 65000.f ? y : 65000.f;           // fp16-overflow backstop
        dst[idx] = (f16)y;
    }
}

// ---------------------------------------------------------------------------
// Kernel 3: fc1 GEMM  C[CHUNK,512] += A[CHUNK,K] * W[512,K]^T  (f16 MFMA)
// m97 structure: 128x128 tile, BK=32, split-K=10, global_load_lds width 16.
// ---------------------------------------------------------------------------
__global__ __launch_bounds__(256) void gemm_fc1(const f16* __restrict__ A,
                                                const f16* __restrict__ B,
                                                float* __restrict__ Cp)
{
    __shared__ f16 As[128 * 32];   // 8 KB
    __shared__ f16 Bs[128 * 32];   // 8 KB

    const int bid = blockIdx.x;
    const int nt = bid & 3;                       // n-tile fastest -> 4 blocks share A tile in L2
    const int mt = (bid >> 2) % MT_CHUNK;
    const int sk = (bid >> 2) / MT_CHUNK;

    const int tid = threadIdx.x;
    const int wave = tid >> 6, lane = tid & 63;
    const int quad = lane >> 4, m16 = lane & 15;
    const int wm = (wave & 1) << 6, wn = (wave >> 1) << 6;

    const size_t K = K_FC1;
    const f16* Ab = A + (size_t)mt * 128 * K + (size_t)sk * KC;
    const f16* Bb = B + (size_t)nt * 128 * K + (size_t)sk * KC;

    // staging geometry: chunk (c,wave) -> LDS [(c*4+wave)*512 .. +512) f16
    // lane l writes 16B at base + l*16 -> row (c*4+wave)*16 + l/4, k (l&3)*8
    const int rrow = (lane >> 2);
    const int kb   = (lane & 3) * 8;

    f32x4 acc[4][4] = {};

    for (int it = 0; it < GITERS; ++it) {
        const f16* Ak = Ab + it * 32;
        const f16* Bk = Bb + it * 32;
        #pragma unroll
        for (int c = 0; c < 2; ++c) {
            int r = ((c * 4 + wave) << 4) + rrow;
            __builtin_amdgcn_global_load_lds(
                (const __attribute__((address_space(1))) void*)(Ak + (size_t)r * K + kb),
                (__attribute__((address_space(3))) void*)(As + (c * 4 + wave) * 512),
                16, 0, 0);
            __builtin_amdgcn_global_load_lds(
                (const __attribute__((address_space(1))) void*)(Bk + (size_t)r * K + kb),
                (__attribute__((address_space(3))) void*)(Bs + (c * 4 + wave) * 512),
                16, 0, 0);
        }
        __syncthreads();

        f16x8 af[4], bf[4];
        #pragma unroll
        for (int i = 0; i < 4; ++i) {
            af[i] = *(const f16x8*)(As + (wm + i * 16 + m16) * 32 + quad * 8);
            bf[i] = *(const f16x8*)(Bs + (wn + i * 16 + m16) * 32 + quad * 8);
        }
        #pragma unroll
        for (int i = 0; i < 4; ++i)
            #pragma unroll
            for (int j = 0; j < 4; ++j)
                acc[i][j] = __builtin_amdgcn_mfma_f32_16x16x32_f16(af[i], bf[j], acc[i][j], 0, 0, 0);
        __syncthreads();
    }

    // C/D layout: col = lane&15, row = quad*4 + reg
    float* Cb = Cp + ((size_t)sk * CHUNK + mt * 128) * 512 + nt * 128;
    #pragma unroll
    for (int i = 0; i < 4; ++i)
        #pragma unroll
        for (int j = 0; j < 4; ++j)
            #pragma unroll
            for (int r = 0; r < 4; ++r) {
                int row = wm + i * 16 + quad * 4 + r;
                int col = wn + j * 16 + m16;
                Cb[(size_t)row * 512 + col] = acc[i][j][r];
            }
}

// ---------------------------------------------------------------------------
// Kernel 4: split-K reduce + *256 (undo A scale) + bias + relu
// ---------------------------------------------------------------------------
__global__ __launch_bounds__(256) void reduce_fc1(const float* __restrict__ Cp,
                                                  const float* __restrict__ b1,
                                                  float* __restrict__ y1)
{
    int idx = blockIdx.x * 256 + threadIdx.x;     // < CHUNK*512
    int nn = idx & 511;
    float s = 0.f;
    #pragma unroll
    for (int k = 0; k < SPLITK; ++k) s += Cp[(size_t)k * (CHUNK * 512) + idx];
    float y = s * 256.0f + b1[nn];
    y1[idx] = y > 0.f ? y : 0.f;
}

// ---------------------------------------------------------------------------
// Kernel 5: fc2 + sigmoid + fc3. 16 samples/block, 128 threads (k index).
// ---------------------------------------------------------------------------
__global__ __launch_bounds__(128) void head_fc23(const float* __restrict__ y1,
                                                 const float* __restrict__ w2,
                                                 const float* __restrict__ b2,
                                                 const float* __restrict__ w3,
                                                 const float* __restrict__ b3,
                                                 float* __restrict__ out, int n0)
{
    __shared__ float Ys[16 * 512];   // 32 KB
    __shared__ float Y2[16 * 128];   // 8 KB
    const int t = threadIdx.x;
    const float4* yb = (const float4*)(y1 + (size_t)blockIdx.x * 16 * 512);
    for (int i = t; i < 16 * 128; i += 128) ((float4*)Ys)[i] = yb[i];
    __syncthreads();

    float acc[16];
    float bk = b2[t];
    #pragma unroll
    for (int s = 0; s < 16; ++s) acc[s] = bk;
    const float4* wr = (const float4*)(w2 + (size_t)t * 512);
    for (int jc = 0; jc < 128; ++jc) {
        float4 w4 = wr[jc];
        #pragma unroll
        for (int s = 0; s < 16; ++s) {
            float4 y4 = *(const float4*)(Ys + s * 512 + jc * 4);
            acc[s] += w4.x * y4.x + w4.y * y4.y + w4.z * y4.z + w4.w * y4.w;
        }
    }
    #pragma unroll
    for (int s = 0; s < 16; ++s) Y2[s * 128 + t] = 1.0f / (1.0f + expf(-acc[s]));
    __syncthreads();

    if (t < 16) {
        float sm = b3[0];
        #pragma unroll 4
        for (int k = 0; k < 128; ++k) sm += Y2[t * 128 + k] * w3[k];
        out[n0 + blockIdx.x * 16 + t] = sm;
    }
}

// ---------------------------------------------------------------------------
extern "C" void kernel_launch(void* const* d_in, const int* in_sizes, int n_in,
                              void* d_out, int out_size, void* d_ws, size_t ws_size,
                              hipStream_t stream)
{
    const float* data = (const float*)d_in[0];
    const float* bn_g = (const float*)d_in[1];
    const float* bn_b = (const float*)d_in[2];
    const float* bn_m = (const float*)d_in[3];
    const float* bn_v = (const float*)d_in[4];
    const float* cw   = (const float*)d_in[5];
    const float* cb   = (const float*)d_in[6];
    const float* fc1w = (const float*)d_in[7];
    const float* fc1b = (const float*)d_in[8];
    const float* fc2w = (const float*)d_in[9];
    const float* fc2b = (const float*)d_in[10];
    const float* fc3w = (const float*)d_in[11];
    const float* fc3b = (const float*)d_in[12];
    float* out = (float*)d_out;

    // workspace layout (total 267,321,344 B ~= 255 MB)
    const size_t A16_BYTES = (size_t)CHUNK * K_FC1 * 2;       // 176,947,200
    const size_t W16_BYTES = (size_t)512 * K_FC1 * 2;         //  44,236,800
    const size_t CP_BYTES  = (size_t)SPLITK * CHUNK * 512 * 4;//  41,943,040
    const size_t Y1_BYTES  = (size_t)CHUNK * 512 * 4;         //   4,194,304
    if (ws_size < A16_BYTES + W16_BYTES + CP_BYTES + Y1_BYTES) return;

    char* ws = (char*)d_ws;
    f16*   A16 = (f16*)ws;
    f16*   W16 = (f16*)(ws + A16_BYTES);
    float* Cp  = (float*)(ws + A16_BYTES + W16_BYTES);
    float* y1  = (float*)(ws + A16_BYTES + W16_BYTES + CP_BYTES);

    conv_w_f16<<<(512 * K_FC1) / (256 * 4), 256, 0, stream>>>(fc1w, W16);

    for (int c = 0; c < 2; ++c) {
        int n0 = c * CHUNK;
        stage_a<<<CHUNK, 256, 0, stream>>>(data, bn_g, bn_b, bn_m, bn_v, cw, cb, A16, n0);
        gemm_fc1<<<4 * MT_CHUNK * SPLITK, 256, 0, stream>>>(A16, W16, Cp);
        reduce_fc1<<<(CHUNK * 512) / 256, 256, 0, stream>>>(Cp, fc1b, y1);
        head_fc23<<<CHUNK / 16, 128, 0, stream>>>(y1, fc2w, fc2b, fc3w, fc3b, out, n0);
    }
}

// Round 2
// 804.256 us; speedup vs baseline: 1.0252x; 1.0252x over previous
//
#include <hip/hip_runtime.h>
#include <cstdint>
#include <cstddef>

// ---------------------------------------------------------------------------
// AlphaNet: features -> BN -> conv(1x3,16) -> relu -> fc1(43200->512) -> relu
//          -> fc2(512->128) -> sigmoid -> fc3(128->1)
// fc1 = f16 MFMA GEMM (A scaled 2^-8). Split-K=27 with fp32 atomic
// accumulation into a 4MB y1 buffer (occupancy fix: 640 -> 1728 blocks).
// ---------------------------------------------------------------------------

typedef _Float16 f16;
typedef f16 f16x8 __attribute__((ext_vector_type(8)));
typedef f16 f16x4 __attribute__((ext_vector_type(4)));
typedef float f32x4 __attribute__((ext_vector_type(4)));

#define N_TOTAL 4096
#define CHUNK   2048               // samples per pipeline pass (2 passes)
#define K_FC1   43200              // 16*270*10
#define SPLITK  27
#define KC      (K_FC1 / SPLITK)   // 1600
#define GITERS  (KC / 32)          // 50
#define MT_CHUNK (CHUNK / 128)     // 16 M-tiles per chunk

__device__ __forceinline__ float fillv(float x) { return isfinite(x) ? x : 0.0f; }

// ---------------------------------------------------------------------------
// Kernel 1: fc1_w fp32 -> f16  (22.1M elements)
// ---------------------------------------------------------------------------
__global__ __launch_bounds__(256) void conv_w_f16(const float* __restrict__ w,
                                                  f16* __restrict__ w16) {
    int t = blockIdx.x * 256 + threadIdx.x;          // grid covers exactly 22118400/4
    float4 v = ((const float4*)w)[t];
    f16x4 o = { (f16)v.x, (f16)v.y, (f16)v.z, (f16)v.w };
    ((f16x4*)w16)[t] = o;
}

// ---------------------------------------------------------------------------
// Kernel 2: per-sample features + BN + conv + relu -> A16 (scaled 2^-8)
// One block per sample, 256 threads.
// Feature rows: corr 0-104 | cov 105-209 | std 210-224 | zs 225-239
//               | ret 240-254 | dl 255-269 ; 12 windows each.
// ---------------------------------------------------------------------------
__global__ __launch_bounds__(256) void stage_a(
    const float* __restrict__ data, const float* __restrict__ bn_g,
    const float* __restrict__ bn_b, const float* __restrict__ bn_m,
    const float* __restrict__ bn_v, const float* __restrict__ conv_w,
    const float* __restrict__ conv_b, f16* __restrict__ A16, int n0)
{
    __shared__ float raw[1800];        // raw window data, becomes spread
    __shared__ float feat[270 * 12];
    __shared__ float cw[48];
    __shared__ float cb[16];
    __shared__ int   pi[105], pj[105];

    const int t = threadIdx.x;
    const int n = n0 + blockIdx.x;
    const float* src = data + (size_t)n * 1800;
    for (int i = t; i < 1800; i += 256) raw[i] = src[i];
    if (t < 48)  cw[t] = conv_w[t];
    if (t < 16)  cb[t] = conv_b[t];
    if (t < 105) {                               // triu_indices(15, k=1) order
        int i = 0, rem = t;
        while (rem >= 14 - i) { rem -= 14 - i; ++i; }
        pi[t] = i; pj[t] = i + 1 + rem;
    }
    __syncthreads();

    // per-(f,w) stats; overwrite raw with spread
    if (t < 180) {
        int f = t / 12, w = t % 12;
        int base = f * 120 + w * 10;
        float x[10];
        #pragma unroll
        for (int s = 0; s < 10; ++s) x[s] = raw[base + s];
        float sum = 0.f;
        #pragma unroll
        for (int s = 0; s < 10; ++s) sum += x[s];
        float mean = sum * 0.1f;
        float ret = x[9] / x[0] - 1.0f;
        float dl = 0.f;
        #pragma unroll
        for (int s = 0; s < 10; ++s) dl += x[s] * ((float)(s + 1) * (1.0f / 55.0f));
        float var = 0.f;
        #pragma unroll
        for (int s = 0; s < 10; ++s) { float d = x[s] - mean; raw[base + s] = d; var += d * d; }
        var *= (1.0f / 9.0f);                    // unbiased
        float sd = sqrtf(var);
        feat[(210 + f) * 12 + w] = fillv(sd);
        feat[(225 + f) * 12 + w] = fillv(mean / sd);
        feat[(240 + f) * 12 + w] = fillv(ret);
        feat[(255 + f) * 12 + w] = fillv(dl);
    }
    __syncthreads();

    // pairwise cov / corr
    for (int q = t; q < 1260; q += 256) {
        int p = q / 12, w = q % 12;
        int i = pi[p], j = pj[p];
        int bi = i * 120 + w * 10, bj = j * 120 + w * 10;
        float cv = 0.f;
        #pragma unroll
        for (int s = 0; s < 10; ++s) cv += raw[bi + s] * raw[bj + s];
        cv *= (1.0f / 9.0f);
        float si = feat[(210 + i) * 12 + w], sj = feat[(210 + j) * 12 + w];
        feat[p * 12 + w]         = fillv(cv / (si * sj) * 0.9f);  // *(S-1)/S
        feat[(105 + p) * 12 + w] = fillv(cv);
    }
    __syncthreads();

    // BatchNorm (eval, C=1 scalar)
    float a  = bn_g[0] * rsqrtf(bn_v[0] + 1e-5f);
    float bb = bn_b[0] - bn_m[0] * a;
    for (int i = t; i < 3240; i += 256) feat[i] = feat[i] * a + bb;
    __syncthreads();

    // conv(1x3) + bias + relu -> scale 2^-8 -> clamp -> f16, vectorized x8
    f16* dst = A16 + (size_t)blockIdx.x * K_FC1;
    for (int v = t; v < K_FC1 / 8; v += 256) {   // 5400 vectors
        int idx0 = v * 8;
        f16x8 ov;
        #pragma unroll
        for (int e = 0; e < 8; ++e) {
            int idx = idx0 + e;
            int oc = idx / 2700;
            int rem = idx - oc * 2700;
            int h = rem / 10;
            int wo = rem - h * 10;
            const float* fr = feat + h * 12 + wo;
            float y = cb[oc] + cw[oc * 3] * fr[0] + cw[oc * 3 + 1] * fr[1] + cw[oc * 3 + 2] * fr[2];
            y = y > 0.f ? y : 0.f;
            y *= 0.00390625f;                    // 2^-8 (exact)
            y = y < 65000.f ? y : 65000.f;       // fp16-overflow backstop
            ov[e] = (f16)y;
        }
        ((f16x8*)dst)[v] = ov;
    }
}

// ---------------------------------------------------------------------------
// Kernel 3: fc1 GEMM  Ysum[CHUNK,512] (+)= A[CHUNK,K] * W[512,K]^T (f16 MFMA)
// 128x128 tile, BK=32, split-K=27 -> 1728 blocks, atomic fp32 accumulation.
// ---------------------------------------------------------------------------
__global__ __launch_bounds__(256) void gemm_fc1(const f16* __restrict__ A,
                                                const f16* __restrict__ B,
                                                float* __restrict__ Ysum)
{
    __shared__ f16 As[128 * 32];   // 8 KB
    __shared__ f16 Bs[128 * 32];   // 8 KB

    const int bid = blockIdx.x;
    const int nt = bid & 3;                       // n-tile fastest -> 4 blocks share A tile in L2
    const int mt = (bid >> 2) % MT_CHUNK;
    const int sk = (bid >> 2) / MT_CHUNK;

    const int tid = threadIdx.x;
    const int wave = tid >> 6, lane = tid & 63;
    const int quad = lane >> 4, m16 = lane & 15;
    const int wm = (wave & 1) << 6, wn = (wave >> 1) << 6;

    const size_t K = K_FC1;
    const f16* Ab = A + (size_t)mt * 128 * K + (size_t)sk * KC;
    const f16* Bb = B + (size_t)nt * 128 * K + (size_t)sk * KC;

    // staging geometry: chunk (c,wave) -> LDS [(c*4+wave)*512 .. +512) f16
    // lane l writes 16B at base + l*16 -> row (c*4+wave)*16 + l/4, k (l&3)*8
    const int rrow = (lane >> 2);
    const int kb   = (lane & 3) * 8;

    f32x4 acc[4][4] = {};

    for (int it = 0; it < GITERS; ++it) {
        const f16* Ak = Ab + it * 32;
        const f16* Bk = Bb + it * 32;
        #pragma unroll
        for (int c = 0; c < 2; ++c) {
            int r = ((c * 4 + wave) << 4) + rrow;
            __builtin_amdgcn_global_load_lds(
                (const __attribute__((address_space(1))) void*)(Ak + (size_t)r * K + kb),
                (__attribute__((address_space(3))) void*)(As + (c * 4 + wave) * 512),
                16, 0, 0);
            __builtin_amdgcn_global_load_lds(
                (const __attribute__((address_space(1))) void*)(Bk + (size_t)r * K + kb),
                (__attribute__((address_space(3))) void*)(Bs + (c * 4 + wave) * 512),
                16, 0, 0);
        }
        __syncthreads();

        f16x8 af[4], bf[4];
        #pragma unroll
        for (int i = 0; i < 4; ++i) {
            af[i] = *(const f16x8*)(As + (wm + i * 16 + m16) * 32 + quad * 8);
            bf[i] = *(const f16x8*)(Bs + (wn + i * 16 + m16) * 32 + quad * 8);
        }
        #pragma unroll
        for (int i = 0; i < 4; ++i)
            #pragma unroll
            for (int j = 0; j < 4; ++j)
                acc[i][j] = __builtin_amdgcn_mfma_f32_16x16x32_f16(af[i], bf[j], acc[i][j], 0, 0, 0);
        __syncthreads();
    }

    // C/D layout: col = lane&15, row = quad*4 + reg. Atomic split-K reduce.
    float* Yb = Ysum + (size_t)(mt * 128) * 512 + nt * 128;
    #pragma unroll
    for (int i = 0; i < 4; ++i)
        #pragma unroll
        for (int j = 0; j < 4; ++j)
            #pragma unroll
            for (int r = 0; r < 4; ++r) {
                int row = wm + i * 16 + quad * 4 + r;
                int col = wn + j * 16 + m16;
                unsafeAtomicAdd(&Yb[(size_t)row * 512 + col], acc[i][j][r]);
            }
}

// ---------------------------------------------------------------------------
// Kernel 4: head = (relu(sum*256+b1)) -> fc2 + sigmoid -> fc3
// 8 samples/block, 128 threads -> 256 blocks per chunk.
// ---------------------------------------------------------------------------
__global__ __launch_bounds__(128) void head_fc23(const float* __restrict__ y1s,
                                                 const float* __restrict__ b1,
                                                 const float* __restrict__ w2,
                                                 const float* __restrict__ b2,
                                                 const float* __restrict__ w3,
                                                 const float* __restrict__ b3,
                                                 float* __restrict__ out, int n0)
{
    __shared__ float Ys[8 * 512];    // 16 KB
    __shared__ float Y2[8 * 128];    // 4 KB
    const int t = threadIdx.x;
    const float4* yb = (const float4*)(y1s + (size_t)blockIdx.x * 8 * 512);
    const float4* b1v = (const float4*)b1;
    for (int i = t; i < 8 * 128; i += 128) {
        float4 s = yb[i];
        float4 bv = b1v[i & 127];
        float4 y;
        y.x = fmaxf(fmaf(s.x, 256.f, bv.x), 0.f);
        y.y = fmaxf(fmaf(s.y, 256.f, bv.y), 0.f);
        y.z = fmaxf(fmaf(s.z, 256.f, bv.z), 0.f);
        y.w = fmaxf(fmaf(s.w, 256.f, bv.w), 0.f);
        ((float4*)Ys)[i] = y;
    }
    __syncthreads();

    float acc[8];
    float bk = b2[t];
    #pragma unroll
    for (int s = 0; s < 8; ++s) acc[s] = bk;
    const float4* wr = (const float4*)(w2 + (size_t)t * 512);
    for (int jc = 0; jc < 128; ++jc) {
        float4 w4 = wr[jc];
        #pragma unroll
        for (int s = 0; s < 8; ++s) {
            float4 y4 = *(const float4*)(Ys + s * 512 + jc * 4);
            acc[s] += w4.x * y4.x + w4.y * y4.y + w4.z * y4.z + w4.w * y4.w;
        }
    }
    #pragma unroll
    for (int s = 0; s < 8; ++s) Y2[s * 128 + t] = 1.0f / (1.0f + expf(-acc[s]));
    __syncthreads();

    if (t < 8) {
        float sm = b3[0];
        #pragma unroll 4
        for (int k = 0; k < 128; ++k) sm += Y2[t * 128 + k] * w3[k];
        out[n0 + blockIdx.x * 8 + t] = sm;
    }
}

// ---------------------------------------------------------------------------
extern "C" void kernel_launch(void* const* d_in, const int* in_sizes, int n_in,
                              void* d_out, int out_size, void* d_ws, size_t ws_size,
                              hipStream_t stream)
{
    const float* data = (const float*)d_in[0];
    const float* bn_g = (const float*)d_in[1];
    const float* bn_b = (const float*)d_in[2];
    const float* bn_m = (const float*)d_in[3];
    const float* bn_v = (const float*)d_in[4];
    const float* cw   = (const float*)d_in[5];
    const float* cb   = (const float*)d_in[6];
    const float* fc1w = (const float*)d_in[7];
    const float* fc1b = (const float*)d_in[8];
    const float* fc2w = (const float*)d_in[9];
    const float* fc2b = (const float*)d_in[10];
    const float* fc3w = (const float*)d_in[11];
    const float* fc3b = (const float*)d_in[12];
    float* out = (float*)d_out;

    // workspace layout (total ~225.6 MB, known-safe < 267 MB)
    const size_t A16_BYTES = (size_t)CHUNK * K_FC1 * 2;       // 176,947,200
    const size_t W16_BYTES = (size_t)512 * K_FC1 * 2;         //  44,236,800
    const size_t Y1_BYTES  = (size_t)CHUNK * 512 * 4;         //   4,194,304
    if (ws_size < A16_BYTES + W16_BYTES + Y1_BYTES) return;

    char* ws = (char*)d_ws;
    f16*   A16 = (f16*)ws;
    f16*   W16 = (f16*)(ws + A16_BYTES);
    float* y1s = (float*)(ws + A16_BYTES + W16_BYTES);

    conv_w_f16<<<(512 * K_FC1) / (256 * 4), 256, 0, stream>>>(fc1w, W16);

    for (int c = 0; c < 2; ++c) {
        int n0 = c * CHUNK;
        hipMemsetAsync(y1s, 0, Y1_BYTES, stream);
        stage_a<<<CHUNK, 256, 0, stream>>>(data, bn_g, bn_b, bn_m, bn_v, cw, cb, A16, n0);
        gemm_fc1<<<4 * MT_CHUNK * SPLITK, 256, 0, stream>>>(A16, W16, y1s);
        head_fc23<<<CHUNK / 8, 128, 0, stream>>>(y1s, fc1b, fc2w, fc2b, fc3w, fc3b, out, n0);
    }
}

// Round 3
// 733.664 us; speedup vs baseline: 1.1239x; 1.0962x over previous
//
#include <hip/hip_runtime.h>
#include <cstdint>
#include <cstddef>

// ---------------------------------------------------------------------------
// AlphaNet: features -> BN -> conv(1x3,16) -> relu -> fc1(43200->512) -> relu
//          -> fc2(512->128) -> sigmoid -> fc3(128->1)
// fc1 = f16 MFMA GEMM (A scaled 2^-8), split-K=27, atomic fp32 reduce.
// R3: pre-tiled A/W [tile][it64][128][64] with XOR-8 bank swizzle baked in,
//     BK=64 (32KB LDS), XCD-aware block swizzle for L2-hot W slices.
// ---------------------------------------------------------------------------

typedef _Float16 f16;
typedef f16 f16x8 __attribute__((ext_vector_type(8)));
typedef float f32x4 __attribute__((ext_vector_type(4)));

#define CHUNK    2048              // samples per pipeline pass (2 passes)
#define K_FC1    43200             // 16*270*10
#define IT_TOT   675               // K_FC1 / 64
#define SPLITK   27
#define IT_BLK   25                // 675 / 27
#define MT_CHUNK 16                // 2048 / 128
#define TILE_ELEMS 8192            // 128*64 f16 per (tile,it) block

__device__ __forceinline__ float fillv(float x) { return isfinite(x) ? x : 0.0f; }

// ---------------------------------------------------------------------------
// Kernel 1: fc1_w fp32 -> f16, retiled to [nt(4)][it(675)][128][64], swizzled:
// 16B unit u of row r stored at unit position u^(r&7).
// One block per (nt,it) = 2700 blocks.
// ---------------------------------------------------------------------------
__global__ __launch_bounds__(256) void retile_w(const float* __restrict__ w,
                                                f16* __restrict__ Wt) {
    const int bid = blockIdx.x;               // nt*675 + it
    const int nt = bid / 675, it = bid % 675;
    const int t = threadIdx.x;
    f16* dst = Wt + (size_t)bid * TILE_ELEMS;
    #pragma unroll
    for (int j = 0; j < 4; ++j) {
        int t2 = t + 256 * j;                 // 0..1023 units
        int r = t2 >> 3, u = t2 & 7;
        const float* s = w + (size_t)(nt * 128 + r) * K_FC1 + it * 64 + u * 8;
        float4 a = *(const float4*)s;
        float4 b = *(const float4*)(s + 4);
        f16x8 o = { (f16)a.x, (f16)a.y, (f16)a.z, (f16)a.w,
                    (f16)b.x, (f16)b.y, (f16)b.z, (f16)b.w };
        int p = u ^ (r & 7);
        *(f16x8*)(dst + (size_t)r * 64 + p * 8) = o;
    }
}

// ---------------------------------------------------------------------------
// Kernel 2: per-sample features + BN + conv + relu -> A_tiled (scaled 2^-8)
// A layout: [mt(16)][it(675)][128][64] f16, same XOR-8 swizzle as W.
// One block per sample, 256 threads.
// ---------------------------------------------------------------------------
__global__ __launch_bounds__(256) void stage_a(
    const float* __restrict__ data, const float* __restrict__ bn_g,
    const float* __restrict__ bn_b, const float* __restrict__ bn_m,
    const float* __restrict__ bn_v, const float* __restrict__ conv_w,
    const float* __restrict__ conv_b, f16* __restrict__ A16, int n0)
{
    __shared__ float raw[1800];        // raw window data, becomes spread
    __shared__ float feat[270 * 12];
    __shared__ float cw[48];
    __shared__ float cb[16];
    __shared__ int   pi[105], pj[105];

    const int t = threadIdx.x;
    const int n = n0 + blockIdx.x;
    const float4* src4 = (const float4*)(data + (size_t)n * 1800);
    for (int i = t; i < 450; i += 256) ((float4*)raw)[i] = src4[i];
    if (t < 48)  cw[t] = conv_w[t];
    if (t < 16)  cb[t] = conv_b[t];
    if (t < 105) {                               // triu_indices(15, k=1) order
        int i = 0, rem = t;
        while (rem >= 14 - i) { rem -= 14 - i; ++i; }
        pi[t] = i; pj[t] = i + 1 + rem;
    }
    __syncthreads();

    // per-(f,w) stats; overwrite raw with spread
    if (t < 180) {
        int f = t / 12, w = t % 12;
        int base = f * 120 + w * 10;
        float x[10];
        #pragma unroll
        for (int s = 0; s < 10; ++s) x[s] = raw[base + s];
        float sum = 0.f;
        #pragma unroll
        for (int s = 0; s < 10; ++s) sum += x[s];
        float mean = sum * 0.1f;
        float ret = x[9] / x[0] - 1.0f;
        float dl = 0.f;
        #pragma unroll
        for (int s = 0; s < 10; ++s) dl += x[s] * ((float)(s + 1) * (1.0f / 55.0f));
        float var = 0.f;
        #pragma unroll
        for (int s = 0; s < 10; ++s) { float d = x[s] - mean; raw[base + s] = d; var += d * d; }
        var *= (1.0f / 9.0f);                    // unbiased
        float sd = sqrtf(var);
        feat[(210 + f) * 12 + w] = fillv(sd);
        feat[(225 + f) * 12 + w] = fillv(mean / sd);
        feat[(240 + f) * 12 + w] = fillv(ret);
        feat[(255 + f) * 12 + w] = fillv(dl);
    }
    __syncthreads();

    // pairwise cov / corr
    for (int q = t; q < 1260; q += 256) {
        int p = q / 12, w = q % 12;
        int i = pi[p], j = pj[p];
        int bi = i * 120 + w * 10, bj = j * 120 + w * 10;
        float cv = 0.f;
        #pragma unroll
        for (int s = 0; s < 10; ++s) cv += raw[bi + s] * raw[bj + s];
        cv *= (1.0f / 9.0f);
        float si = feat[(210 + i) * 12 + w], sj = feat[(210 + j) * 12 + w];
        feat[p * 12 + w]         = fillv(cv / (si * sj) * 0.9f);  // *(S-1)/S
        feat[(105 + p) * 12 + w] = fillv(cv);
    }
    __syncthreads();

    // BatchNorm (eval, C=1 scalar)
    float a  = bn_g[0] * rsqrtf(bn_v[0] + 1e-5f);
    float bb = bn_b[0] - bn_m[0] * a;
    for (int i = t; i < 3240; i += 256) feat[i] = feat[i] * a + bb;
    __syncthreads();

    // conv(1x3) + bias + relu -> scale 2^-8 -> clamp -> f16 -> tiled+swizzled
    const int s_idx = blockIdx.x;                // sample within chunk
    const int mt = s_idx >> 7, r = s_idx & 127, rx = r & 7;
    f16* base = A16 + (size_t)mt * IT_TOT * TILE_ELEMS + (size_t)r * 64;
    for (int v = t; v < K_FC1 / 8; v += 256) {   // 5400 16B units
        int idx0 = v * 8;
        f16x8 ov;
        #pragma unroll
        for (int e = 0; e < 8; ++e) {
            int idx = idx0 + e;
            int oc = idx / 2700;
            int rem = idx - oc * 2700;
            int h = rem / 10;
            int wo = rem - h * 10;
            const float* fr = feat + h * 12 + wo;
            float y = cb[oc] + cw[oc * 3] * fr[0] + cw[oc * 3 + 1] * fr[1] + cw[oc * 3 + 2] * fr[2];
            y = y > 0.f ? y : 0.f;
            y *= 0.00390625f;                    // 2^-8 (exact)
            y = y < 65000.f ? y : 65000.f;       // fp16-overflow backstop
            ov[e] = (f16)y;
        }
        int it = v >> 3, u = v & 7;
        int p = u ^ rx;
        *(f16x8*)(base + (size_t)it * TILE_ELEMS + p * 8) = ov;
    }
}

// ---------------------------------------------------------------------------
// Kernel 3: fc1 GEMM  Ysum[CHUNK,512] (+)= A * W^T (f16 MFMA)
// 128x128 tile, BK=64, split-K=27 -> 1728 blocks, atomic fp32 accumulation.
// XCD swizzle: xcd=bid&7 -> nt=xcd>>1, mt fastest => W k-slice L2-hot.
// ---------------------------------------------------------------------------
__global__ __launch_bounds__(256) void gemm_fc1(const f16* __restrict__ A,
                                                const f16* __restrict__ W,
                                                float* __restrict__ Ysum)
{
    __shared__ f16 As[128 * 64];   // 16 KB
    __shared__ f16 Bs[128 * 64];   // 16 KB

    const int bid = blockIdx.x;
    const int xcd = bid & 7, slot = bid >> 3;     // 216 slots per XCD
    const int nt = xcd >> 1;
    const int idx = slot + (xcd & 1) * 216;       // 0..431 -> (mt, sk)
    const int mt = idx & 15, sk = idx >> 4;       // sk 0..26

    const int tid = threadIdx.x;
    const int wave = tid >> 6, lane = tid & 63;
    const int quad = lane >> 4, m16 = lane & 15;
    const int wm = (wave & 1) << 6, wn = (wave >> 1) << 6;
    const int px = m16 & 7;                       // swizzle key (row&7)

    const f16* Ab = A + (size_t)(mt * IT_TOT + sk * IT_BLK) * TILE_ELEMS;
    const f16* Bb = W + (size_t)(nt * IT_TOT + sk * IT_BLK) * TILE_ELEMS;
    const int soff = (wave * 4) * 512 + lane * 8; // staging src/dst base (elems)

    f32x4 acc[4][4] = {};

    for (int it = 0; it < IT_BLK; ++it) {
        const f16* Ak = Ab + (size_t)it * TILE_ELEMS;
        const f16* Bk = Bb + (size_t)it * TILE_ELEMS;
        #pragma unroll
        for (int j = 0; j < 4; ++j) {
            __builtin_amdgcn_global_load_lds(
                (const __attribute__((address_space(1))) void*)(Ak + soff + j * 512),
                (__attribute__((address_space(3))) void*)(As + (wave * 4 + j) * 512),
                16, 0, 0);
            __builtin_amdgcn_global_load_lds(
                (const __attribute__((address_space(1))) void*)(Bk + soff + j * 512),
                (__attribute__((address_space(3))) void*)(Bs + (wave * 4 + j) * 512),
                16, 0, 0);
        }
        __syncthreads();

        f16x8 af[2][4], bf[2][4];
        #pragma unroll
        for (int h = 0; h < 2; ++h) {
            int p = (((h << 2) + quad) ^ px) * 8;
            #pragma unroll
            for (int i = 0; i < 4; ++i) {
                af[h][i] = *(const f16x8*)(As + (wm + i * 16 + m16) * 64 + p);
                bf[h][i] = *(const f16x8*)(Bs + (wn + i * 16 + m16) * 64 + p);
            }
        }
        #pragma unroll
        for (int h = 0; h < 2; ++h)
            #pragma unroll
            for (int i = 0; i < 4; ++i)
                #pragma unroll
                for (int j = 0; j < 4; ++j)
                    acc[i][j] = __builtin_amdgcn_mfma_f32_16x16x32_f16(af[h][i], bf[h][j], acc[i][j], 0, 0, 0);
        __syncthreads();
    }

    // C/D layout: col = lane&15, row = quad*4 + reg. Atomic split-K reduce.
    float* Yb = Ysum + (size_t)(mt * 128) * 512 + nt * 128;
    #pragma unroll
    for (int i = 0; i < 4; ++i)
        #pragma unroll
        for (int j = 0; j < 4; ++j)
            #pragma unroll
            for (int r = 0; r < 4; ++r) {
                int row = wm + i * 16 + quad * 4 + r;
                int col = wn + j * 16 + m16;
                unsafeAtomicAdd(&Yb[(size_t)row * 512 + col], acc[i][j][r]);
            }
}

// ---------------------------------------------------------------------------
// Kernel 4: head = (relu(sum*256+b1)) -> fc2 + sigmoid -> fc3
// 8 samples/block, 128 threads -> 256 blocks per chunk.
// ---------------------------------------------------------------------------
__global__ __launch_bounds__(128) void head_fc23(const float* __restrict__ y1s,
                                                 const float* __restrict__ b1,
                                                 const float* __restrict__ w2,
                                                 const float* __restrict__ b2,
                                                 const float* __restrict__ w3,
                                                 const float* __restrict__ b3,
                                                 float* __restrict__ out, int n0)
{
    __shared__ float Ys[8 * 512];    // 16 KB
    __shared__ float Y2[8 * 128];    // 4 KB
    const int t = threadIdx.x;
    const float4* yb = (const float4*)(y1s + (size_t)blockIdx.x * 8 * 512);
    const float4* b1v = (const float4*)b1;
    for (int i = t; i < 8 * 128; i += 128) {
        float4 s = yb[i];
        float4 bv = b1v[i & 127];
        float4 y;
        y.x = fmaxf(fmaf(s.x, 256.f, bv.x), 0.f);
        y.y = fmaxf(fmaf(s.y, 256.f, bv.y), 0.f);
        y.z = fmaxf(fmaf(s.z, 256.f, bv.z), 0.f);
        y.w = fmaxf(fmaf(s.w, 256.f, bv.w), 0.f);
        ((float4*)Ys)[i] = y;
    }
    __syncthreads();

    float acc[8];
    float bk = b2[t];
    #pragma unroll
    for (int s = 0; s < 8; ++s) acc[s] = bk;
    const float4* wr = (const float4*)(w2 + (size_t)t * 512);
    for (int jc = 0; jc < 128; ++jc) {
        float4 w4 = wr[jc];
        #pragma unroll
        for (int s = 0; s < 8; ++s) {
            float4 y4 = *(const float4*)(Ys + s * 512 + jc * 4);
            acc[s] += w4.x * y4.x + w4.y * y4.y + w4.z * y4.z + w4.w * y4.w;
        }
    }
    #pragma unroll
    for (int s = 0; s < 8; ++s) Y2[s * 128 + t] = 1.0f / (1.0f + expf(-acc[s]));
    __syncthreads();

    if (t < 8) {
        float sm = b3[0];
        #pragma unroll 4
        for (int k = 0; k < 128; ++k) sm += Y2[t * 128 + k] * w3[k];
        out[n0 + blockIdx.x * 8 + t] = sm;
    }
}

// ---------------------------------------------------------------------------
extern "C" void kernel_launch(void* const* d_in, const int* in_sizes, int n_in,
                              void* d_out, int out_size, void* d_ws, size_t ws_size,
                              hipStream_t stream)
{
    const float* data = (const float*)d_in[0];
    const float* bn_g = (const float*)d_in[1];
    const float* bn_b = (const float*)d_in[2];
    const float* bn_m = (const float*)d_in[3];
    const float* bn_v = (const float*)d_in[4];
    const float* cw   = (const float*)d_in[5];
    const float* cb   = (const float*)d_in[6];
    const float* fc1w = (const float*)d_in[7];
    const float* fc1b = (const float*)d_in[8];
    const float* fc2w = (const float*)d_in[9];
    const float* fc2b = (const float*)d_in[10];
    const float* fc3w = (const float*)d_in[11];
    const float* fc3b = (const float*)d_in[12];
    float* out = (float*)d_out;

    // workspace layout (total ~225.6 MB, known-safe)
    const size_t A16_BYTES = (size_t)CHUNK * K_FC1 * 2;       // 176,947,200
    const size_t W16_BYTES = (size_t)512 * K_FC1 * 2;         //  44,236,800
    const size_t Y1_BYTES  = (size_t)CHUNK * 512 * 4;         //   4,194,304
    if (ws_size < A16_BYTES + W16_BYTES + Y1_BYTES) return;

    char* ws = (char*)d_ws;
    f16*   A16 = (f16*)ws;
    f16*   W16 = (f16*)(ws + A16_BYTES);
    float* y1s = (float*)(ws + A16_BYTES + W16_BYTES);

    retile_w<<<4 * IT_TOT, 256, 0, stream>>>(fc1w, W16);

    for (int c = 0; c < 2; ++c) {
        int n0 = c * CHUNK;
        hipMemsetAsync(y1s, 0, Y1_BYTES, stream);
        stage_a<<<CHUNK, 256, 0, stream>>>(data, bn_g, bn_b, bn_m, bn_v, cw, cb, A16, n0);
        gemm_fc1<<<8 * 216, 256, 0, stream>>>(A16, W16, y1s);
        head_fc23<<<CHUNK / 8, 128, 0, stream>>>(y1s, fc1b, fc2w, fc2b, fc3w, fc3b, out, n0);
    }
}